// Round 4
// baseline (515.923 us; speedup 1.0000x reference)
//
#include <hip/hip_runtime.h>

constexpr int B = 8, S = 2048, D = 256;
constexpr int TQ = 16;              // query rows per block -> 66.3 KB LDS -> 2 blocks/CU
constexpr float SCALE = 0.0625f;    // 1/sqrt(256)
constexpr int PSTRIDE = 2056;       // 2048 + 8 bf16 pad -> 2-way bank aliasing (free)

typedef __attribute__((ext_vector_type(8))) short bf16x8;  // 8 bf16 in 4 VGPRs
typedef __attribute__((ext_vector_type(4))) float f32x4;

__device__ __forceinline__ short f2bf(float f) {
    union { float f; unsigned u; } c; c.f = f;
    unsigned u = c.u + 0x7fffu + ((c.u >> 16) & 1u);   // RNE
    return (short)(u >> 16);
}

// ---- fused pre-pass: convQ | convK | transposeV | packMask in ONE launch ----
// grid layout: [0,4096) convQ, [4096,8192) convK, [8192,9216) transposeV,
//              [9216,13312) packMask (ballot version, 4 rows per 256-thr block)
__global__ __launch_bounds__(256) void prepass(
    const float* __restrict__ q, const float* __restrict__ k,
    const float* __restrict__ v, const int* __restrict__ mask,
    short* __restrict__ qb, short* __restrict__ kb,
    short* __restrict__ vtb, unsigned short* __restrict__ pm)
{
    __shared__ float tile[64][65];
    const int blk = blockIdx.x;
    const int tid = threadIdx.x;

    if (blk < 8192) {
        // ---- conv q/k: fp32 -> bf16, float4 granularity ----
        const float* in = (blk < 4096) ? q : k;
        short* out = (blk < 4096) ? qb : kb;
        int i = (blk & 4095) * 256 + tid;
        float4 x = ((const float4*)in)[i];
        short4 o; o.x = f2bf(x.x); o.y = f2bf(x.y); o.z = f2bf(x.z); o.w = f2bf(x.w);
        ((short4*)out)[i] = o;
    } else if (blk < 9216) {
        // ---- transpose V: [B][S][D] fp32 -> [B][D][S] bf16 ----
        int blk2 = blk - 8192;
        int b = blk2 >> 7, rem = blk2 & 127;
        int d0 = (rem & 3) * 64, k0 = (rem >> 2) * 64;
        int tr = tid >> 4, tc = tid & 15;
        const float* vb = v + (size_t)b * S * D;
        #pragma unroll
        for (int r = 0; r < 4; ++r) {
            int key = r * 16 + tr;
            float4 x = *(const float4*)(vb + (size_t)(k0 + key) * D + d0 + tc * 4);
            tile[key][tc * 4 + 0] = x.x; tile[key][tc * 4 + 1] = x.y;
            tile[key][tc * 4 + 2] = x.z; tile[key][tc * 4 + 3] = x.w;
        }
        __syncthreads();
        short* vtbb = vtb + (size_t)b * D * S;
        #pragma unroll
        for (int r = 0; r < 4; ++r) {
            int d = r * 16 + tr;
            short4 o;
            o.x = f2bf(tile[tc * 4 + 0][d]); o.y = f2bf(tile[tc * 4 + 1][d]);
            o.z = f2bf(tile[tc * 4 + 2][d]); o.w = f2bf(tile[tc * 4 + 3][d]);
            *(short4*)(vtbb + (size_t)(d0 + d) * S + k0 + tc * 4) = o;
        }
    } else {
        // ---- pack mask via ballot: 64 coalesced 4B loads -> 64 bits per ballot ----
        // pm[rowlin][g][l16] bit nt = (mask[rowlin][g*256 + nt*16 + l16] != 0)
        int t2 = blk - 9216;                 // 0..4095
        int w = tid >> 6, lane = tid & 63;
        int l16 = lane & 15;
        int rowlin = t2 * 4 + w;             // b*S + row
        const int* mrow = mask + (size_t)rowlin * S;
        unsigned short* pmrow = pm + (size_t)rowlin * 128;
        #pragma unroll
        for (int g = 0; g < 8; ++g) {
            unsigned v16 = 0;
            #pragma unroll
            for (int u = 0; u < 4; ++u) {
                int col = g * 256 + u * 64 + lane;
                unsigned long long bal = __ballot(mrow[col] != 0);
                unsigned nib = (unsigned)((bal >> l16) & 1ull)
                             | (unsigned)((bal >> (l16 + 16)) & 1ull) << 1
                             | (unsigned)((bal >> (l16 + 32)) & 1ull) << 2
                             | (unsigned)((bal >> (l16 + 48)) & 1ull) << 3;
                v16 |= nib << (u * 4);
            }
            if (lane < 16) pmrow[g * 16 + l16] = (unsigned short)v16;
        }
    }
}

// ---- main fused kernel: 512 threads (8 waves), 1 block = 16 q-rows x 1 batch ----
// LDS: p_lds 16*2056*2 = 64.3 KB + red 0.5 KB -> 66.3 KB -> 2 blocks/CU.
// Regs (measured R1): 64 VGPR + 64 AGPR = 128/wave -> 16 waves/CU. (512,4) enforces.
__global__ __launch_bounds__(512, 4) void attn_mfma(
    const short* __restrict__ qb, const short* __restrict__ kb,
    const short* __restrict__ vtb, const unsigned short* __restrict__ pmg,
    float* __restrict__ outg, float* __restrict__ attng)
{
    const int b = blockIdx.y;
    const int i0 = blockIdx.x * TQ;
    const int tid = threadIdx.x;
    const int wave = tid >> 6, lane = tid & 63;
    const int quad = lane >> 4, l16 = lane & 15;

    __shared__ short p_lds[TQ][PSTRIDE];
    __shared__ float red[8][TQ];

    // prefetch packed mask: one ushort per owned row (4 rows), consumed in phase B.
    // pm index: ((b*S + row)*8 + wave)*16 + l16 ; row = i0 + quad*4 + r
    unsigned pmv[4];
    {
        const unsigned short* pmb = pmg + (((size_t)b * S + i0 + quad * 4) * 8 + wave) * 16 + l16;
        #pragma unroll
        for (int r = 0; r < 4; ++r)
            pmv[r] = pmb[(size_t)r * 128];
    }

    // ---------- phase A: scores = Q K^T (wave w owns keys [w*256, w*256+256)) ----------
    bf16x8 aq[8];
    const short* qbase = qb + ((size_t)b * S + i0) * D;
    #pragma unroll
    for (int ks = 0; ks < 8; ++ks)
        aq[ks] = *(const bf16x8*)(qbase + (size_t)l16 * D + ks * 32 + quad * 8);

    f32x4 acc[16];
    #pragma unroll
    for (int nt = 0; nt < 16; ++nt)
        acc[nt] = f32x4{0.f, 0.f, 0.f, 0.f};

    const short* kbase = kb + (size_t)b * S * D;
    #pragma unroll
    for (int nt = 0; nt < 16; ++nt) {
        const int n0 = wave * 256 + nt * 16;
        bf16x8 bk[8];
        #pragma unroll
        for (int ks = 0; ks < 8; ++ks)
            bk[ks] = *(const bf16x8*)(kbase + (size_t)(n0 + l16) * D + ks * 32 + quad * 8);
        #pragma unroll
        for (int ks = 0; ks < 8; ++ks)
            acc[nt] = __builtin_amdgcn_mfma_f32_16x16x32_bf16(aq[ks], bk[ks], acc[nt], 0, 0, 0);
    }

    // ---------- phase B: mask (packed bits), exp, row-sum (pure VALU) ----------
    // C-layout: row_local = quad*4 + r, col = wave*256 + nt*16 + l16
    float rsum[4];
    #pragma unroll
    for (int r = 0; r < 4; ++r) rsum[r] = 0.f;

    #pragma unroll
    for (int nt = 0; nt < 16; ++nt) {
        #pragma unroll
        for (int r = 0; r < 4; ++r) {
            float s = acc[nt][r] * SCALE;
            float sv = ((pmv[r] >> nt) & 1u) ? s : -1e9f;
            float e = __expf(sv);               // exp(-1e9) underflows to 0 == reference
            acc[nt][r] = e;
            rsum[r] += e;
        }
    }
    // reduce across the 16 lanes sharing a row (xor bits 0..3 stay in the quad-group)
    #pragma unroll
    for (int r = 0; r < 4; ++r) {
        float v = rsum[r];
        v += __shfl_xor(v, 1); v += __shfl_xor(v, 2);
        v += __shfl_xor(v, 4); v += __shfl_xor(v, 8);
        rsum[r] = v;
        if (l16 == 0) red[wave][quad * 4 + r] = v;
    }
    __syncthreads();

    float inv[4];
    #pragma unroll
    for (int r = 0; r < 4; ++r) {
        float tot = 0.f;
        #pragma unroll
        for (int w = 0; w < 8; ++w) tot += red[w][quad * 4 + r];
        inv[r] = 1.0f / tot;
    }

    // normalize, write attn (batched: row chunks temporally adjacent for L2
    // write-combining -- R3 showed interleaving these stores 3x's WRITE_SIZE),
    // stash P (bf16) in LDS for phase C. The pre-barrier store drain of this
    // block overlaps the co-resident block's compute (2 blocks/CU).
    {
        float* abase = attng + ((size_t)b * S + i0 + quad * 4) * S;
        #pragma unroll
        for (int nt = 0; nt < 16; ++nt) {
            const int col = wave * 256 + nt * 16 + l16;
            #pragma unroll
            for (int r = 0; r < 4; ++r) {
                float p = acc[nt][r] * inv[r];
                abase[(size_t)r * S + col] = p;
                p_lds[quad * 4 + r][col] = f2bf(p);
            }
        }
    }
    __syncthreads();

    // ---------- phase C: out = P V (wave w owns dims [w*32, w*32+32)) ----------
    f32x4 oacc[2];
    #pragma unroll
    for (int nc = 0; nc < 2; ++nc) oacc[nc] = f32x4{0.f, 0.f, 0.f, 0.f};

    const short* vbase = vtb + (size_t)b * D * S;
    const int nb = wave * 32;
    for (int ks = 0; ks < 64; ++ks) {
        bf16x8 ap, bv[2];
        ap = *(const bf16x8*)&p_lds[l16][ks * 32 + quad * 8];
        #pragma unroll
        for (int nc = 0; nc < 2; ++nc)
            bv[nc] = *(const bf16x8*)(vbase + (size_t)(nb + nc * 16 + l16) * S + ks * 32 + quad * 8);
        #pragma unroll
        for (int nc = 0; nc < 2; ++nc)
            oacc[nc] = __builtin_amdgcn_mfma_f32_16x16x32_bf16(ap, bv[nc], oacc[nc], 0, 0, 0);
    }

    #pragma unroll
    for (int nc = 0; nc < 2; ++nc)
        #pragma unroll
        for (int r = 0; r < 4; ++r) {
            int row = i0 + quad * 4 + r;
            int col = nb + nc * 16 + l16;
            outg[((size_t)b * S + row) * D + col] = oacc[nc][r];
        }
}

extern "C" void kernel_launch(void* const* d_in, const int* in_sizes, int n_in,
                              void* d_out, int out_size, void* d_ws, size_t ws_size,
                              hipStream_t stream) {
    const float* q    = (const float*)d_in[0];
    const float* k    = (const float*)d_in[1];
    const float* v    = (const float*)d_in[2];
    const int*   mask = (const int*)d_in[3];
    float* out  = (float*)d_out;
    float* attn = out + (size_t)B * S * D;     // tuple order: (out, attn)

    const size_t N = (size_t)B * S * D;        // 4,194,304 elements
    short* qb  = (short*)d_ws;                 // 8 MB
    short* kb  = qb + N;                       // 8 MB
    short* vtb = kb + N;                       // 8 MB (transposed V)
    unsigned short* pm = (unsigned short*)(vtb + N);  // 4 MB packed mask

    prepass<<<dim3(13312), 256, 0, stream>>>(q, k, v, mask, qb, kb, vtb, pm);
    attn_mfma<<<dim3(S / TQ, B), 512, 0, stream>>>(qb, kb, vtb, pm, out, attn);
}

// Round 5
// 412.404 us; speedup vs baseline: 1.2510x; 1.2510x over previous
//
#include <hip/hip_runtime.h>

constexpr int B = 8, S = 2048, D = 256;
constexpr int TQ = 32;              // query rows per block (main kernel)
constexpr float SCALE = 0.0625f;    // 1/sqrt(256)
constexpr int PSTRIDE = 2056;       // 2048 + 8 bf16 pad -> 2-way bank aliasing (free)

typedef __attribute__((ext_vector_type(8))) short bf16x8;  // 8 bf16 in 4 VGPRs
typedef __attribute__((ext_vector_type(4))) float f32x4;

__device__ __forceinline__ short f2bf(float f) {
    union { float f; unsigned u; } c; c.f = f;
    unsigned u = c.u + 0x7fffu + ((c.u >> 16) & 1u);   // RNE
    return (short)(u >> 16);
}

// ---- fused pre-pass: convQ | convK | transposeV | packMask in ONE launch ----
// grid layout: [0,4096) convQ, [4096,8192) convK, [8192,9216) transposeV,
//              [9216,13312) packMask (ballot version, 4 rows per 256-thr block)
__global__ __launch_bounds__(256) void prepass(
    const float* __restrict__ q, const float* __restrict__ k,
    const float* __restrict__ v, const int* __restrict__ mask,
    short* __restrict__ qb, short* __restrict__ kb,
    short* __restrict__ vtb, unsigned short* __restrict__ pm)
{
    __shared__ float tile[64][65];
    const int blk = blockIdx.x;
    const int tid = threadIdx.x;

    if (blk < 8192) {
        // ---- conv q/k: fp32 -> bf16, float4 granularity ----
        const float* in = (blk < 4096) ? q : k;
        short* out = (blk < 4096) ? qb : kb;
        int i = (blk & 4095) * 256 + tid;
        float4 x = ((const float4*)in)[i];
        short4 o; o.x = f2bf(x.x); o.y = f2bf(x.y); o.z = f2bf(x.z); o.w = f2bf(x.w);
        ((short4*)out)[i] = o;
    } else if (blk < 9216) {
        // ---- transpose V: [B][S][D] fp32 -> [B][D][S] bf16 ----
        int blk2 = blk - 8192;
        int b = blk2 >> 7, rem = blk2 & 127;
        int d0 = (rem & 3) * 64, k0 = (rem >> 2) * 64;
        int tr = tid >> 4, tc = tid & 15;
        const float* vb = v + (size_t)b * S * D;
        #pragma unroll
        for (int r = 0; r < 4; ++r) {
            int key = r * 16 + tr;
            float4 x = *(const float4*)(vb + (size_t)(k0 + key) * D + d0 + tc * 4);
            tile[key][tc * 4 + 0] = x.x; tile[key][tc * 4 + 1] = x.y;
            tile[key][tc * 4 + 2] = x.z; tile[key][tc * 4 + 3] = x.w;
        }
        __syncthreads();
        short* vtbb = vtb + (size_t)b * D * S;
        #pragma unroll
        for (int r = 0; r < 4; ++r) {
            int d = r * 16 + tr;
            short4 o;
            o.x = f2bf(tile[tc * 4 + 0][d]); o.y = f2bf(tile[tc * 4 + 1][d]);
            o.z = f2bf(tile[tc * 4 + 2][d]); o.w = f2bf(tile[tc * 4 + 3][d]);
            *(short4*)(vtbb + (size_t)(d0 + d) * S + k0 + tc * 4) = o;
        }
    } else {
        // ---- pack mask via ballot: 64 coalesced 4B loads -> 64 bits per ballot ----
        // pm[rowlin][g][l16] bit nt = (mask[rowlin][g*256 + nt*16 + l16] != 0)
        int t2 = blk - 9216;                 // 0..4095
        int w = tid >> 6, lane = tid & 63;
        int l16 = lane & 15;
        int rowlin = t2 * 4 + w;             // b*S + row
        const int* mrow = mask + (size_t)rowlin * S;
        unsigned short* pmrow = pm + (size_t)rowlin * 128;
        #pragma unroll
        for (int g = 0; g < 8; ++g) {
            unsigned v16 = 0;
            #pragma unroll
            for (int u = 0; u < 4; ++u) {
                int col = g * 256 + u * 64 + lane;
                unsigned long long bal = __ballot(mrow[col] != 0);
                unsigned nib = (unsigned)((bal >> l16) & 1ull)
                             | (unsigned)((bal >> (l16 + 16)) & 1ull) << 1
                             | (unsigned)((bal >> (l16 + 32)) & 1ull) << 2
                             | (unsigned)((bal >> (l16 + 48)) & 1ull) << 3;
                v16 |= nib << (u * 4);
            }
            if (lane < 16) pmrow[g * 16 + l16] = (unsigned short)v16;
        }
    }
}

// ---- main fused kernel: 512 threads (8 waves), 1 block = 32 q-rows x 1 batch ----
// LDS: p_lds 32*2056*2 = 128.5 KB + red 1 KB -> 1 block/CU, 2 waves/SIMD.
// XCD-batch affinity: 1-D grid, batch = blk & 7. Round-robin dispatch puts all
// 64 blocks of batch b on XCD b -> K_b + V_b^T = 2 MB becomes L2-resident
// (was: 8 batches x 2 MB = 16 MB thrashing each 4 MB L2, spilling ~1 GB of
// K/V stream to L3 -- the ~100 us unexplained stall; R4's TQ=16 doubling the
// stream and adding +104 us is the consistency check for this model).
__global__ __launch_bounds__(512, 2) void attn_mfma(
    const short* __restrict__ qb, const short* __restrict__ kb,
    const short* __restrict__ vtb, const unsigned short* __restrict__ pmg,
    float* __restrict__ outg, float* __restrict__ attng)
{
    const int b = blockIdx.x & 7;              // XCD-affine batch
    const int i0 = (blockIdx.x >> 3) * TQ;     // q-tile within batch
    const int tid = threadIdx.x;
    const int wave = tid >> 6, lane = tid & 63;
    const int quad = lane >> 4, l16 = lane & 15;

    __shared__ short p_lds[TQ][PSTRIDE];
    __shared__ float red[8][TQ];

    // prefetch packed mask: one ushort per owned row (8 rows), consumed in phase B.
    unsigned pmv[2][4];
    {
        const unsigned short* pmb = pmg + (((size_t)b * S + i0 + quad * 4) * 8 + wave) * 16 + l16;
        #pragma unroll
        for (int mt = 0; mt < 2; ++mt)
            #pragma unroll
            for (int r = 0; r < 4; ++r)
                pmv[mt][r] = pmb[(size_t)(mt * 16 + r) * 128];
    }

    // ---------- phase A: scores = Q K^T (wave w owns keys [w*256, w*256+256)) ----------
    bf16x8 aq[2][8];
    const short* qbase = qb + ((size_t)b * S + i0) * D;
    #pragma unroll
    for (int mt = 0; mt < 2; ++mt)
        #pragma unroll
        for (int ks = 0; ks < 8; ++ks)
            aq[mt][ks] = *(const bf16x8*)(qbase + (size_t)(mt * 16 + l16) * D + ks * 32 + quad * 8);

    f32x4 acc[2][16];
    #pragma unroll
    for (int mt = 0; mt < 2; ++mt)
        #pragma unroll
        for (int nt = 0; nt < 16; ++nt)
            acc[mt][nt] = f32x4{0.f, 0.f, 0.f, 0.f};

    const short* kbase = kb + (size_t)b * S * D;
    #pragma unroll
    for (int nt = 0; nt < 16; ++nt) {
        const int n0 = wave * 256 + nt * 16;
        bf16x8 bk[8];
        #pragma unroll
        for (int ks = 0; ks < 8; ++ks)
            bk[ks] = *(const bf16x8*)(kbase + (size_t)(n0 + l16) * D + ks * 32 + quad * 8);
        #pragma unroll
        for (int ks = 0; ks < 8; ++ks) {
            acc[0][nt] = __builtin_amdgcn_mfma_f32_16x16x32_bf16(aq[0][ks], bk[ks], acc[0][nt], 0, 0, 0);
            acc[1][nt] = __builtin_amdgcn_mfma_f32_16x16x32_bf16(aq[1][ks], bk[ks], acc[1][nt], 0, 0, 0);
        }
    }

    // ---------- phase B: mask (packed bits), exp, row-sum (pure VALU) ----------
    float rsum[2][4];
    #pragma unroll
    for (int mt = 0; mt < 2; ++mt)
        #pragma unroll
        for (int r = 0; r < 4; ++r) rsum[mt][r] = 0.f;

    #pragma unroll
    for (int mt = 0; mt < 2; ++mt) {
        #pragma unroll
        for (int nt = 0; nt < 16; ++nt) {
            #pragma unroll
            for (int r = 0; r < 4; ++r) {
                float s = acc[mt][nt][r] * SCALE;
                float sv = ((pmv[mt][r] >> nt) & 1u) ? s : -1e9f;
                float e = __expf(sv);           // exp(-1e9) underflows to 0 == reference
                acc[mt][nt][r] = e;
                rsum[mt][r] += e;
            }
        }
    }
    #pragma unroll
    for (int mt = 0; mt < 2; ++mt)
        #pragma unroll
        for (int r = 0; r < 4; ++r) {
            float v = rsum[mt][r];
            v += __shfl_xor(v, 1); v += __shfl_xor(v, 2);
            v += __shfl_xor(v, 4); v += __shfl_xor(v, 8);
            rsum[mt][r] = v;
            if (l16 == 0) red[wave][mt * 16 + quad * 4 + r] = v;
        }
    __syncthreads();

    float inv[2][4];
    #pragma unroll
    for (int mt = 0; mt < 2; ++mt)
        #pragma unroll
        for (int r = 0; r < 4; ++r) {
            float tot = 0.f;
            #pragma unroll
            for (int w = 0; w < 8; ++w) tot += red[w][mt * 16 + quad * 4 + r];
            inv[mt][r] = 1.0f / tot;
        }

    // normalize, write attn (batched: a row's chunks stay temporally adjacent
    // for L2 write-combining -- R3 proved interleaving 3x's WRITE_SIZE),
    // stash P (bf16) in LDS for phase C.
    #pragma unroll
    for (int mt = 0; mt < 2; ++mt) {
        float* abase = attng + ((size_t)b * S + i0 + mt * 16 + quad * 4) * S;
        #pragma unroll
        for (int nt = 0; nt < 16; ++nt) {
            const int col = wave * 256 + nt * 16 + l16;
            #pragma unroll
            for (int r = 0; r < 4; ++r) {
                float p = acc[mt][nt][r] * inv[mt][r];
                abase[(size_t)r * S + col] = p;
                p_lds[mt * 16 + quad * 4 + r][col] = f2bf(p);
            }
        }
    }
    __syncthreads();

    // ---------- phase C: out = P V (wave w owns dims [w*32, w*32+32)) ----------
    f32x4 oacc[2][2];
    #pragma unroll
    for (int mt = 0; mt < 2; ++mt)
        #pragma unroll
        for (int nc = 0; nc < 2; ++nc) oacc[mt][nc] = f32x4{0.f, 0.f, 0.f, 0.f};

    const short* vbase = vtb + (size_t)b * D * S;
    const int nb = wave * 32;
    for (int ks = 0; ks < 64; ++ks) {
        bf16x8 ap[2], bv[2];
        #pragma unroll
        for (int mt = 0; mt < 2; ++mt)
            ap[mt] = *(const bf16x8*)&p_lds[mt * 16 + l16][ks * 32 + quad * 8];
        #pragma unroll
        for (int nc = 0; nc < 2; ++nc)
            bv[nc] = *(const bf16x8*)(vbase + (size_t)(nb + nc * 16 + l16) * S + ks * 32 + quad * 8);
        #pragma unroll
        for (int mt = 0; mt < 2; ++mt)
            #pragma unroll
            for (int nc = 0; nc < 2; ++nc)
                oacc[mt][nc] = __builtin_amdgcn_mfma_f32_16x16x32_bf16(ap[mt], bv[nc], oacc[mt][nc], 0, 0, 0);
    }

    #pragma unroll
    for (int mt = 0; mt < 2; ++mt)
        #pragma unroll
        for (int nc = 0; nc < 2; ++nc)
            #pragma unroll
            for (int r = 0; r < 4; ++r) {
                int row = i0 + mt * 16 + quad * 4 + r;
                int col = nb + nc * 16 + l16;
                outg[((size_t)b * S + row) * D + col] = oacc[mt][nc][r];
            }
}

extern "C" void kernel_launch(void* const* d_in, const int* in_sizes, int n_in,
                              void* d_out, int out_size, void* d_ws, size_t ws_size,
                              hipStream_t stream) {
    const float* q    = (const float*)d_in[0];
    const float* k    = (const float*)d_in[1];
    const float* v    = (const float*)d_in[2];
    const int*   mask = (const int*)d_in[3];
    float* out  = (float*)d_out;
    float* attn = out + (size_t)B * S * D;     // tuple order: (out, attn)

    const size_t N = (size_t)B * S * D;        // 4,194,304 elements
    short* qb  = (short*)d_ws;                 // 8 MB
    short* kb  = qb + N;                       // 8 MB
    short* vtb = kb + N;                       // 8 MB (transposed V)
    unsigned short* pm = (unsigned short*)(vtb + N);  // 4 MB packed mask

    prepass<<<dim3(13312), 256, 0, stream>>>(q, k, v, mask, qb, kb, vtb, pm);
    attn_mfma<<<dim3((S / TQ) * B), 512, 0, stream>>>(qb, kb, vtb, pm, out, attn);
}

// Round 6
// 411.003 us; speedup vs baseline: 1.2553x; 1.0034x over previous
//
#include <hip/hip_runtime.h>

constexpr int B = 8, S = 2048, D = 256;
constexpr int TQ = 32;              // query rows per block (main kernel)
constexpr float SCALE = 0.0625f;    // 1/sqrt(256)
constexpr int PSTRIDE = 2056;       // 2048 + 8 bf16 pad -> 2-way bank aliasing (free)

typedef __attribute__((ext_vector_type(8))) short bf16x8;  // 8 bf16 in 4 VGPRs
typedef __attribute__((ext_vector_type(4))) float f32x4;

__device__ __forceinline__ short f2bf(float f) {
    union { float f; unsigned u; } c; c.f = f;
    unsigned u = c.u + 0x7fffu + ((c.u >> 16) & 1u);   // RNE
    return (short)(u >> 16);
}

// ---- minimal pre-pass: convK | transposeV only ----
// grid: [0,4096) convK, [4096,5120) transposeV
// (pack_mask folded into attn_mfma: its 134 MB read cost +53 us of prepass
//  time R0->R2; conv_q folded too -- Q has no cross-block reuse.)
__global__ __launch_bounds__(256) void prepass(
    const float* __restrict__ k, const float* __restrict__ v,
    short* __restrict__ kb, short* __restrict__ vtb)
{
    __shared__ float tile[64][65];
    const int blk = blockIdx.x;
    const int tid = threadIdx.x;

    if (blk < 4096) {
        // ---- conv k: fp32 -> bf16, float4 granularity ----
        int i = blk * 256 + tid;
        float4 x = ((const float4*)k)[i];
        short4 o; o.x = f2bf(x.x); o.y = f2bf(x.y); o.z = f2bf(x.z); o.w = f2bf(x.w);
        ((short4*)kb)[i] = o;
    } else {
        // ---- transpose V: [B][S][D] fp32 -> [B][D][S] bf16 ----
        int blk2 = blk - 4096;
        int b = blk2 >> 7, rem = blk2 & 127;
        int d0 = (rem & 3) * 64, k0 = (rem >> 2) * 64;
        int tr = tid >> 4, tc = tid & 15;
        const float* vb = v + (size_t)b * S * D;
        #pragma unroll
        for (int r = 0; r < 4; ++r) {
            int key = r * 16 + tr;
            float4 x = *(const float4*)(vb + (size_t)(k0 + key) * D + d0 + tc * 4);
            tile[key][tc * 4 + 0] = x.x; tile[key][tc * 4 + 1] = x.y;
            tile[key][tc * 4 + 2] = x.z; tile[key][tc * 4 + 3] = x.w;
        }
        __syncthreads();
        short* vtbb = vtb + (size_t)b * D * S;
        #pragma unroll
        for (int r = 0; r < 4; ++r) {
            int d = r * 16 + tr;
            short4 o;
            o.x = f2bf(tile[tc * 4 + 0][d]); o.y = f2bf(tile[tc * 4 + 1][d]);
            o.z = f2bf(tile[tc * 4 + 2][d]); o.w = f2bf(tile[tc * 4 + 3][d]);
            *(short4*)(vtbb + (size_t)(d0 + d) * S + k0 + tc * 4) = o;
        }
    }
}

// ---- main fused kernel: 512 threads (8 waves), 1 block = 32 q-rows x 1 batch ----
// LDS: p_lds 128.5 KB + red 1 KB + pm_lds 8 KB = 137.5 KB -> 1 block/CU.
// XCD-batch affinity (R5: cut FETCH 3x): batch = blk & 7.
// Mask is ballot-packed in-kernel: 32-deep batched coalesced loads at kernel
// start (latency amortized; R0's failure was 128 serial dependent loads).
__global__ __launch_bounds__(512, 2) void attn_mfma(
    const float* __restrict__ qf, const short* __restrict__ kb,
    const short* __restrict__ vtb, const int* __restrict__ maskg,
    float* __restrict__ outg, float* __restrict__ attng)
{
    const int b = blockIdx.x & 7;              // XCD-affine batch
    const int i0 = (blockIdx.x >> 3) * TQ;     // q-tile within batch
    const int tid = threadIdx.x;
    const int wave = tid >> 6, lane = tid & 63;
    const int quad = lane >> 4, l16 = lane & 15;

    __shared__ short p_lds[TQ][PSTRIDE];
    __shared__ float red[8][TQ];
    __shared__ unsigned short pm_lds[TQ][8][16];  // [row][g][l16] bit nt <-> col g*256+nt*16+l16

    // ---------- phase 0: ballot-pack mask into LDS (wave w packs rows w*4..w*4+3) ----------
    {
        const int* mrow_base = maskg + ((size_t)b * S + i0 + wave * 4) * S;
        #pragma unroll 1
        for (int rr = 0; rr < 4; ++rr) {
            const int* mrow = mrow_base + (size_t)rr * S;
            int mv[32];
            #pragma unroll
            for (int g = 0; g < 8; ++g)
                #pragma unroll
                for (int u = 0; u < 4; ++u)
                    mv[g * 4 + u] = mrow[g * 256 + u * 64 + lane];   // 32 coalesced loads, batched
            #pragma unroll
            for (int g = 0; g < 8; ++g) {
                unsigned v16 = 0;
                #pragma unroll
                for (int u = 0; u < 4; ++u) {
                    unsigned long long bal = __ballot(mv[g * 4 + u] != 0);
                    unsigned nib = (unsigned)((bal >> l16) & 1ull)
                                 | (unsigned)((bal >> (l16 + 16)) & 1ull) << 1
                                 | (unsigned)((bal >> (l16 + 32)) & 1ull) << 2
                                 | (unsigned)((bal >> (l16 + 48)) & 1ull) << 3;
                    v16 |= nib << (u * 4);
                }
                if (lane < 16) pm_lds[wave * 4 + rr][g][l16] = (unsigned short)v16;
            }
        }
    }
    __syncthreads();

    // ---------- phase A: scores = Q K^T (wave w owns keys [w*256, w*256+256)) ----------
    // Q converted fp32 -> bf16 in-register (no cross-block reuse -> no prepass)
    bf16x8 aq[2][8];
    const float* qbase = qf + ((size_t)b * S + i0) * D;
    #pragma unroll
    for (int mt = 0; mt < 2; ++mt)
        #pragma unroll
        for (int ks = 0; ks < 8; ++ks) {
            const float* p = qbase + (size_t)(mt * 16 + l16) * D + ks * 32 + quad * 8;
            float4 x0 = *(const float4*)p;
            float4 x1 = *(const float4*)(p + 4);
            bf16x8 a;
            a[0] = f2bf(x0.x); a[1] = f2bf(x0.y); a[2] = f2bf(x0.z); a[3] = f2bf(x0.w);
            a[4] = f2bf(x1.x); a[5] = f2bf(x1.y); a[6] = f2bf(x1.z); a[7] = f2bf(x1.w);
            aq[mt][ks] = a;
        }

    f32x4 acc[2][16];
    #pragma unroll
    for (int mt = 0; mt < 2; ++mt)
        #pragma unroll
        for (int nt = 0; nt < 16; ++nt)
            acc[mt][nt] = f32x4{0.f, 0.f, 0.f, 0.f};

    const short* kbase = kb + (size_t)b * S * D;
    #pragma unroll
    for (int nt = 0; nt < 16; ++nt) {
        const int n0 = wave * 256 + nt * 16;
        bf16x8 bk[8];
        #pragma unroll
        for (int ks = 0; ks < 8; ++ks)
            bk[ks] = *(const bf16x8*)(kbase + (size_t)(n0 + l16) * D + ks * 32 + quad * 8);
        #pragma unroll
        for (int ks = 0; ks < 8; ++ks) {
            acc[0][nt] = __builtin_amdgcn_mfma_f32_16x16x32_bf16(aq[0][ks], bk[ks], acc[0][nt], 0, 0, 0);
            acc[1][nt] = __builtin_amdgcn_mfma_f32_16x16x32_bf16(aq[1][ks], bk[ks], acc[1][nt], 0, 0, 0);
        }
    }

    // ---------- phase B: mask (LDS packed bits), exp, row-sum (pure VALU) ----------
    // C-layout: row_local = mt*16 + quad*4 + r, col = wave*256 + nt*16 + l16
    unsigned pmv[2][4];
    #pragma unroll
    for (int mt = 0; mt < 2; ++mt)
        #pragma unroll
        for (int r = 0; r < 4; ++r)
            pmv[mt][r] = pm_lds[mt * 16 + quad * 4 + r][wave][l16];

    float rsum[2][4];
    #pragma unroll
    for (int mt = 0; mt < 2; ++mt)
        #pragma unroll
        for (int r = 0; r < 4; ++r) rsum[mt][r] = 0.f;

    #pragma unroll
    for (int mt = 0; mt < 2; ++mt) {
        #pragma unroll
        for (int nt = 0; nt < 16; ++nt) {
            #pragma unroll
            for (int r = 0; r < 4; ++r) {
                float s = acc[mt][nt][r] * SCALE;
                float sv = ((pmv[mt][r] >> nt) & 1u) ? s : -1e9f;
                float e = __expf(sv);           // exp(-1e9) underflows to 0 == reference
                acc[mt][nt][r] = e;
                rsum[mt][r] += e;
            }
        }
    }
    #pragma unroll
    for (int mt = 0; mt < 2; ++mt)
        #pragma unroll
        for (int r = 0; r < 4; ++r) {
            float v = rsum[mt][r];
            v += __shfl_xor(v, 1); v += __shfl_xor(v, 2);
            v += __shfl_xor(v, 4); v += __shfl_xor(v, 8);
            rsum[mt][r] = v;
            if (l16 == 0) red[wave][mt * 16 + quad * 4 + r] = v;
        }
    __syncthreads();

    float inv[2][4];
    #pragma unroll
    for (int mt = 0; mt < 2; ++mt)
        #pragma unroll
        for (int r = 0; r < 4; ++r) {
            float tot = 0.f;
            #pragma unroll
            for (int w = 0; w < 8; ++w) tot += red[w][mt * 16 + quad * 4 + r];
            inv[mt][r] = 1.0f / tot;
        }

    // normalize, write attn (batched: a row's chunks stay temporally adjacent
    // for L2 write-combining -- R3 proved interleaving 3x's WRITE_SIZE),
    // stash P (bf16) in LDS for phase C.
    #pragma unroll
    for (int mt = 0; mt < 2; ++mt) {
        float* abase = attng + ((size_t)b * S + i0 + mt * 16 + quad * 4) * S;
        #pragma unroll
        for (int nt = 0; nt < 16; ++nt) {
            const int col = wave * 256 + nt * 16 + l16;
            #pragma unroll
            for (int r = 0; r < 4; ++r) {
                float p = acc[mt][nt][r] * inv[mt][r];
                abase[(size_t)r * S + col] = p;
                p_lds[mt * 16 + quad * 4 + r][col] = f2bf(p);
            }
        }
    }
    __syncthreads();

    // ---------- phase C: out = P V (wave w owns dims [w*32, w*32+32)) ----------
    f32x4 oacc[2][2];
    #pragma unroll
    for (int mt = 0; mt < 2; ++mt)
        #pragma unroll
        for (int nc = 0; nc < 2; ++nc) oacc[mt][nc] = f32x4{0.f, 0.f, 0.f, 0.f};

    const short* vbase = vtb + (size_t)b * D * S;
    const int nb = wave * 32;
    for (int ks = 0; ks < 64; ++ks) {
        bf16x8 ap[2], bv[2];
        #pragma unroll
        for (int mt = 0; mt < 2; ++mt)
            ap[mt] = *(const bf16x8*)&p_lds[mt * 16 + l16][ks * 32 + quad * 8];
        #pragma unroll
        for (int nc = 0; nc < 2; ++nc)
            bv[nc] = *(const bf16x8*)(vbase + (size_t)(nb + nc * 16 + l16) * S + ks * 32 + quad * 8);
        #pragma unroll
        for (int mt = 0; mt < 2; ++mt)
            #pragma unroll
            for (int nc = 0; nc < 2; ++nc)
                oacc[mt][nc] = __builtin_amdgcn_mfma_f32_16x16x32_bf16(ap[mt], bv[nc], oacc[mt][nc], 0, 0, 0);
    }

    #pragma unroll
    for (int mt = 0; mt < 2; ++mt)
        #pragma unroll
        for (int nc = 0; nc < 2; ++nc)
            #pragma unroll
            for (int r = 0; r < 4; ++r) {
                int row = i0 + mt * 16 + quad * 4 + r;
                int col = nb + nc * 16 + l16;
                outg[((size_t)b * S + row) * D + col] = oacc[mt][nc][r];
            }
}

extern "C" void kernel_launch(void* const* d_in, const int* in_sizes, int n_in,
                              void* d_out, int out_size, void* d_ws, size_t ws_size,
                              hipStream_t stream) {
    const float* q    = (const float*)d_in[0];
    const float* k    = (const float*)d_in[1];
    const float* v    = (const float*)d_in[2];
    const int*   mask = (const int*)d_in[3];
    float* out  = (float*)d_out;
    float* attn = out + (size_t)B * S * D;     // tuple order: (out, attn)

    const size_t N = (size_t)B * S * D;        // 4,194,304 elements
    short* kb  = (short*)d_ws;                 // 8 MB
    short* vtb = kb + N;                       // 8 MB (transposed V)

    prepass<<<dim3(5120), 256, 0, stream>>>(k, v, kb, vtb);
    attn_mfma<<<dim3((S / TQ) * B), 512, 0, stream>>>(q, kb, vtb, mask, out, attn);
}

// Round 7
// 409.523 us; speedup vs baseline: 1.2598x; 1.0036x over previous
//
#include <hip/hip_runtime.h>

constexpr int B = 8, S = 2048, D = 256;
constexpr int TQ = 32;              // query rows per block (main kernel)
constexpr float SCALE = 0.0625f;    // 1/sqrt(256)
constexpr int PSTRIDE = 2056;       // 2048 + 8 bf16 pad -> 2-way bank aliasing (free)

typedef __attribute__((ext_vector_type(8))) short bf16x8;  // 8 bf16 in 4 VGPRs
typedef __attribute__((ext_vector_type(4))) float f32x4;

__device__ __forceinline__ short f2bf(float f) {
    union { float f; unsigned u; } c; c.f = f;
    unsigned u = c.u + 0x7fffu + ((c.u >> 16) & 1u);   // RNE
    return (short)(u >> 16);
}

// ---- minimal pre-pass: convK | transposeV only ----
// grid: [0,4096) convK, [4096,5120) transposeV
__global__ __launch_bounds__(256) void prepass(
    const float* __restrict__ k, const float* __restrict__ v,
    short* __restrict__ kb, short* __restrict__ vtb)
{
    __shared__ float tile[64][65];
    const int blk = blockIdx.x;
    const int tid = threadIdx.x;

    if (blk < 4096) {
        // ---- conv k: fp32 -> bf16, float4 granularity ----
        int i = blk * 256 + tid;
        float4 x = ((const float4*)k)[i];
        short4 o; o.x = f2bf(x.x); o.y = f2bf(x.y); o.z = f2bf(x.z); o.w = f2bf(x.w);
        ((short4*)kb)[i] = o;
    } else {
        // ---- transpose V: [B][S][D] fp32 -> [B][D][S] bf16 ----
        int blk2 = blk - 4096;
        int b = blk2 >> 7, rem = blk2 & 127;
        int d0 = (rem & 3) * 64, k0 = (rem >> 2) * 64;
        int tr = tid >> 4, tc = tid & 15;
        const float* vb = v + (size_t)b * S * D;
        #pragma unroll
        for (int r = 0; r < 4; ++r) {
            int key = r * 16 + tr;
            float4 x = *(const float4*)(vb + (size_t)(k0 + key) * D + d0 + tc * 4);
            tile[key][tc * 4 + 0] = x.x; tile[key][tc * 4 + 1] = x.y;
            tile[key][tc * 4 + 2] = x.z; tile[key][tc * 4 + 3] = x.w;
        }
        __syncthreads();
        short* vtbb = vtb + (size_t)b * D * S;
        #pragma unroll
        for (int r = 0; r < 4; ++r) {
            int d = r * 16 + tr;
            short4 o;
            o.x = f2bf(tile[tc * 4 + 0][d]); o.y = f2bf(tile[tc * 4 + 1][d]);
            o.z = f2bf(tile[tc * 4 + 2][d]); o.w = f2bf(tile[tc * 4 + 3][d]);
            *(short4*)(vtbb + (size_t)(d0 + d) * S + k0 + tc * 4) = o;
        }
    }
}

// ---- main fused kernel: 512 threads (8 waves), 1 block = 32 q-rows x 1 batch ----
// SWAPPED QK^T: acc[mt][nt] = mfma(bk, aq) holds S^T fragments:
//   acc[mt][nt][r] = S[key = wave*256 + nt*16 + quad*4 + r][q = i0 + mt*16 + l16]
// -> each thread owns 4 CONSECUTIVE key-cols of one q-row, so the mask read is
//    one int4 (16B) and the attn write is one float4 (16B). The 4 B/lane scalar
//    streams were the ~2 TB/s cap that made R0-R6 a zero-sum relocation game.
// LDS: p_lds 128.5 KB + red 1 KB -> 1 block/CU. XCD-batch affinity kept (R5).
__global__ __launch_bounds__(512, 2) void attn_mfma(
    const float* __restrict__ qf, const short* __restrict__ kb,
    const short* __restrict__ vtb, const int* __restrict__ maskg,
    float* __restrict__ outg, float* __restrict__ attng)
{
    const int b = blockIdx.x & 7;              // XCD-affine batch
    const int i0 = (blockIdx.x >> 3) * TQ;     // q-tile within batch
    const int tid = threadIdx.x;
    const int wave = tid >> 6, lane = tid & 63;
    const int quad = lane >> 4, l16 = lane & 15;

    __shared__ short p_lds[TQ][PSTRIDE];
    __shared__ float red[8][TQ];

    // ---------- phase 0: mask -> in-register bitmasks (int4 = 16 B/lane loads) ----------
    // mb[mt] bit (nt*4 + r) = mask[b][i0+mt*16+l16][wave*256 + nt*16 + quad*4 + r]
    unsigned long long mb[2];
    #pragma unroll
    for (int mt = 0; mt < 2; ++mt) {
        const int* mrow = maskg + ((size_t)b * S + i0 + mt * 16 + l16) * S + wave * 256 + quad * 4;
        unsigned long long bits = 0;
        #pragma unroll
        for (int c = 0; c < 2; ++c) {          // 2 batches of 8 int4 loads in flight
            int4 t[8];
            #pragma unroll
            for (int j = 0; j < 8; ++j)
                t[j] = *(const int4*)(mrow + (c * 8 + j) * 16);
            #pragma unroll
            for (int j = 0; j < 8; ++j) {
                const int nt = c * 8 + j;
                unsigned long long nib = (t[j].x != 0 ? 1ull : 0ull)
                                       | (t[j].y != 0 ? 2ull : 0ull)
                                       | (t[j].z != 0 ? 4ull : 0ull)
                                       | (t[j].w != 0 ? 8ull : 0ull);
                bits |= nib << (nt * 4);
            }
        }
        mb[mt] = bits;
    }

    // ---------- phase A: S^T = K Q^T (swapped operands) ----------
    // Q converted fp32 -> bf16 in-register (no cross-block reuse -> no prepass)
    bf16x8 aq[2][8];
    const float* qbase = qf + ((size_t)b * S + i0) * D;
    #pragma unroll
    for (int mt = 0; mt < 2; ++mt)
        #pragma unroll
        for (int ks = 0; ks < 8; ++ks) {
            const float* p = qbase + (size_t)(mt * 16 + l16) * D + ks * 32 + quad * 8;
            float4 x0 = *(const float4*)p;
            float4 x1 = *(const float4*)(p + 4);
            bf16x8 a;
            a[0] = f2bf(x0.x); a[1] = f2bf(x0.y); a[2] = f2bf(x0.z); a[3] = f2bf(x0.w);
            a[4] = f2bf(x1.x); a[5] = f2bf(x1.y); a[6] = f2bf(x1.z); a[7] = f2bf(x1.w);
            aq[mt][ks] = a;
        }

    f32x4 acc[2][16];
    #pragma unroll
    for (int mt = 0; mt < 2; ++mt)
        #pragma unroll
        for (int nt = 0; nt < 16; ++nt)
            acc[mt][nt] = f32x4{0.f, 0.f, 0.f, 0.f};

    const short* kbase = kb + (size_t)b * S * D;
    #pragma unroll
    for (int nt = 0; nt < 16; ++nt) {
        const int n0 = wave * 256 + nt * 16;
        bf16x8 bk[8];
        #pragma unroll
        for (int ks = 0; ks < 8; ++ks)
            bk[ks] = *(const bf16x8*)(kbase + (size_t)(n0 + l16) * D + ks * 32 + quad * 8);
        #pragma unroll
        for (int ks = 0; ks < 8; ++ks) {
            // swapped: first operand K -> C row = key, second Q -> C col = q
            acc[0][nt] = __builtin_amdgcn_mfma_f32_16x16x32_bf16(bk[ks], aq[0][ks], acc[0][nt], 0, 0, 0);
            acc[1][nt] = __builtin_amdgcn_mfma_f32_16x16x32_bf16(bk[ks], aq[1][ks], acc[1][nt], 0, 0, 0);
        }
    }

    // ---------- phase B: mask (register bits), exp, row-sum ----------
    float rsum[2] = {0.f, 0.f};
    #pragma unroll
    for (int mt = 0; mt < 2; ++mt) {
        #pragma unroll
        for (int nt = 0; nt < 16; ++nt) {
            #pragma unroll
            for (int r = 0; r < 4; ++r) {
                float e = ((mb[mt] >> (nt * 4 + r)) & 1ull)
                        ? __expf(acc[mt][nt][r] * SCALE) : 0.0f;
                acc[mt][nt][r] = e;
                rsum[mt] += e;
            }
        }
    }
    // reduce across the 4 quads holding the same q-row (lane bits 4,5)
    #pragma unroll
    for (int mt = 0; mt < 2; ++mt) {
        float v = rsum[mt];
        v += __shfl_xor(v, 16); v += __shfl_xor(v, 32);
        if (quad == 0) red[wave][mt * 16 + l16] = v;
    }
    __syncthreads();

    float inv[2];
    #pragma unroll
    for (int mt = 0; mt < 2; ++mt) {
        float tot = 0.f;
        #pragma unroll
        for (int w = 0; w < 8; ++w) tot += red[w][mt * 16 + l16];
        inv[mt] = 1.0f / tot;
    }

    // normalize; attn write = float4/lane, batched (R3: batching preserves L2
    // write-combining); p_lds stash = short4/lane.
    #pragma unroll
    for (int mt = 0; mt < 2; ++mt) {
        float* arow = attng + ((size_t)b * S + i0 + mt * 16 + l16) * S + wave * 256 + quad * 4;
        #pragma unroll
        for (int nt = 0; nt < 16; ++nt) {
            float4 p4; short4 pb;
            float p0 = acc[mt][nt][0] * inv[mt];
            float p1 = acc[mt][nt][1] * inv[mt];
            float p2 = acc[mt][nt][2] * inv[mt];
            float p3 = acc[mt][nt][3] * inv[mt];
            p4.x = p0; p4.y = p1; p4.z = p2; p4.w = p3;
            pb.x = f2bf(p0); pb.y = f2bf(p1); pb.z = f2bf(p2); pb.w = f2bf(p3);
            *(float4*)(arow + nt * 16) = p4;
            *(short4*)&p_lds[mt * 16 + l16][wave * 256 + nt * 16 + quad * 4] = pb;
        }
    }
    __syncthreads();

    // ---------- phase C: out = P V (wave w owns dims [w*32, w*32+32)) ----------
    f32x4 oacc[2][2];
    #pragma unroll
    for (int mt = 0; mt < 2; ++mt)
        #pragma unroll
        for (int nc = 0; nc < 2; ++nc) oacc[mt][nc] = f32x4{0.f, 0.f, 0.f, 0.f};

    const short* vbase = vtb + (size_t)b * D * S;
    const int nb = wave * 32;
    for (int ks = 0; ks < 64; ++ks) {
        bf16x8 ap[2], bv[2];
        #pragma unroll
        for (int mt = 0; mt < 2; ++mt)
            ap[mt] = *(const bf16x8*)&p_lds[mt * 16 + l16][ks * 32 + quad * 8];
        #pragma unroll
        for (int nc = 0; nc < 2; ++nc)
            bv[nc] = *(const bf16x8*)(vbase + (size_t)(nb + nc * 16 + l16) * S + ks * 32 + quad * 8);
        #pragma unroll
        for (int mt = 0; mt < 2; ++mt)
            #pragma unroll
            for (int nc = 0; nc < 2; ++nc)
                oacc[mt][nc] = __builtin_amdgcn_mfma_f32_16x16x32_bf16(ap[mt], bv[nc], oacc[mt][nc], 0, 0, 0);
    }

    #pragma unroll
    for (int mt = 0; mt < 2; ++mt)
        #pragma unroll
        for (int nc = 0; nc < 2; ++nc)
            #pragma unroll
            for (int r = 0; r < 4; ++r) {
                int row = i0 + mt * 16 + quad * 4 + r;
                int col = nb + nc * 16 + l16;
                outg[((size_t)b * S + row) * D + col] = oacc[mt][nc][r];
            }
}

extern "C" void kernel_launch(void* const* d_in, const int* in_sizes, int n_in,
                              void* d_out, int out_size, void* d_ws, size_t ws_size,
                              hipStream_t stream) {
    const float* q    = (const float*)d_in[0];
    const float* k    = (const float*)d_in[1];
    const float* v    = (const float*)d_in[2];
    const int*   mask = (const int*)d_in[3];
    float* out  = (float*)d_out;
    float* attn = out + (size_t)B * S * D;     // tuple order: (out, attn)

    const size_t N = (size_t)B * S * D;        // 4,194,304 elements
    short* kb  = (short*)d_ws;                 // 8 MB
    short* vtb = kb + N;                       // 8 MB (transposed V)

    prepass<<<dim3(5120), 256, 0, stream>>>(k, v, kb, vtb);
    attn_mfma<<<dim3((S / TQ) * B), 512, 0, stream>>>(q, kb, vtb, mask, out, attn);
}